// Round 11
// baseline (387.865 us; speedup 1.0000x reference)
//
#include <hip/hip_runtime.h>
#include <math.h>

#define N_NODES 50000
#define N_EDGES 160000
#define NB 32
#define C1N 25000
#define C2N 12500
#define EPB 128
#define GPB 128

// ---- workspace layout (in floats) ----
#define OFF_AGG1 0
#define SZ_AGG1 (N_NODES*32)
#define OFF_AGG2 (OFF_AGG1+SZ_AGG1)
#define SZ_AGG2  (C1N*64)
#define NEG_TOTAL (OFF_AGG2+SZ_AGG2)        // [0,NEG_TOTAL) = -inf
#define OFF_GSUM NEG_TOTAL                  // B*64 (zeroed)
#define OFF_GCNT (OFF_GSUM + NB*64)         // B
#define OFF_CMAX (OFF_GCNT + NB)            // 1 (+3 pad)
#define OFF_HIST (OFF_CMAX + 4)             // N int counters (zeroed)
#define ZERO_END (OFF_HIST + N_NODES)
#define OFF_PERM ZERO_END                   // E ints (dst-sorted edge ids)
#define OFF_X2   (OFF_PERM + N_EDGES)       // C1*32 (written direct)
#define OFF_POS2 (OFF_X2 + C1N*32)          // C1*2
#define OFF_X4   (OFF_POS2 + C1N*2)         // C2*64 (written direct)
#define OFF_CART (OFF_X4 + C2N*64)          // E*2
#define OFF_BB1  (OFF_CART + N_EDGES*2)     // 26*2*512 bf16 = 13312 floats
#define OFF_BB2  (OFF_BB1 + 13312)          // 26*4*512 bf16 = 26624 floats

typedef __attribute__((ext_vector_type(8))) short short8;
typedef __attribute__((ext_vector_type(4))) float f32x4;

__device__ __forceinline__ void atomicMaxFloat(float* addr, float v) {
    if (v >= 0.0f) atomicMax((int*)addr, __float_as_int(v + 0.0f)); // +0.0 canonicalizes -0
    else           atomicMin((unsigned int*)addr, __float_as_uint(v));
}
__device__ __forceinline__ float eluf(float v) { return v > 0.0f ? v : expm1f(v); }
__device__ __forceinline__ unsigned short f2bf(float f) {
    unsigned int u = __float_as_uint(f);
    u += 0x7FFFu + ((u >> 16) & 1u);   // round-to-nearest-even
    return (unsigned short)(u >> 16);
}

__global__ void k_init(float* ws) {
    int i = blockIdx.x*256 + threadIdx.x;
    if (i < ZERO_END) ws[i] = (i < NEG_TOTAL) ? -__builtin_inff() : 0.0f;
}

// ---- counting sort by dst: histogram -> exclusive scan -> scatter
__global__ void k_hist(const int* __restrict__ dstArr, float* ws) {
    int e = blockIdx.x*256 + threadIdx.x;
    if (e < N_EDGES) atomicAdd((int*)(ws+OFF_HIST) + dstArr[e], 1);
}

__global__ __launch_bounds__(1024) void k_scan(float* ws) {
    int* hist = (int*)(ws + OFF_HIST);
    __shared__ int part[1024];
    int t = threadIdx.x;
    const int PER = (N_NODES + 1023) / 1024;     // 49
    int base = t*PER;
    int s = 0;
    for (int i = 0; i < PER; ++i) {
        int idx = base + i;
        if (idx < N_NODES) s += hist[idx];
    }
    part[t] = s; __syncthreads();
    for (int off = 1; off < 1024; off <<= 1) {
        int v = (t >= off) ? part[t-off] : 0;
        __syncthreads();
        part[t] += v;
        __syncthreads();
    }
    int running = part[t] - s;                   // exclusive prefix of this chunk
    for (int i = 0; i < PER; ++i) {
        int idx = base + i;
        if (idx < N_NODES) { int h = hist[idx]; hist[idx] = running; running += h; }
    }
}

__global__ void k_scatter(const int* __restrict__ dstArr, float* ws) {
    int e = blockIdx.x*256 + threadIdx.x;
    if (e < N_EDGES) {
        int p = atomicAdd((int*)(ws+OFF_HIST) + dstArr[e], 1);
        ((int*)(ws+OFF_PERM))[p] = e;
    }
}

// ---- build bf16 B-fragment bank for the [832 x O] GEMM.
// Bf[(h*(O/16)+ntg)*512 + l*8 + j] = W[h*32 + (l>>4)*8+j][ntg*16 + (l&15)]
// W[kk][o]: rows kk=h*32+i; h<25 -> w2[h][i*O+o]; h==25 -> b2[i*O+o]
template<int O>
__global__ void k_swzf(const float* __restrict__ w2, const float* __restrict__ b2,
                       unsigned short* __restrict__ Bf) {
    const int TOT = 26*(O/16)*512;
    int idx = blockIdx.x*256 + threadIdx.x;
    if (idx >= TOT) return;
    int t = idx >> 9;
    int l = (idx >> 3) & 63, j = idx & 7;
    int h = t / (O/16), ntg = t % (O/16);
    int i = (l >> 4)*8 + j;
    int o = ntg*16 + (l & 15);
    float v = (h < 25) ? w2[h*(32*O) + i*O + o] : b2[i*O + o];
    Bf[idx] = f2bf(v);
}

// ---- edge phase as MFMA GEMM over dst-sorted edges:
// [128 edges x 832] @ [832 x 32 cols/dispatch]; z[e,h*32+i]=r[e,h]*x[src_e,i];
// r in-register; W staged in LDS shared by 8 waves; same-dst rows merged
// in-register before the global atomic (sorted => ~deg-length runs).
template<int O, int NTILES, int NTOFF_T, int SELF, int HASCM, int SHIFT>
__global__ __launch_bounds__(512, 4) void k_edgemm(
    const float* __restrict__ X, const unsigned short* __restrict__ Bf,
    const float* __restrict__ w1, const float* __restrict__ b1,
    const int* __restrict__ srcArr, const int* __restrict__ dstArr,
    const int* __restrict__ permArr,
    const float* __restrict__ eaArr, const float* __restrict__ cmaxp,
    float* __restrict__ agg)
{
    __shared__ __align__(16) unsigned short Wl[26*NTILES*512];
    __shared__ int src_s[EPB], dst_s[EPB], eid_s[EPB];
    int tid = threadIdx.x;
    int e0 = blockIdx.x * EPB;
    if (tid < EPB) {
        int e = permArr[e0+tid];
        int s = srcArr[e], d = dstArr[e];
        if (SHIFT) { s >>= 1; d >>= 1; }
        src_s[tid] = s; dst_s[tid] = d; eid_s[tid] = e;
    }
    const int NU4 = 26*NTILES*64;      // uint4 chunks of Wl
    for (int idx = tid; idx < NU4; idx += 512) {
        int q = idx & 63, nt = (idx >> 6) % NTILES, h = idx / (64*NTILES);
        ((uint4*)Wl)[idx] = ((const uint4*)Bf)[(h*(O/16) + NTOFF_T + nt)*64 + q];
    }
    float sc = 1.0f, off = 0.0f;
    if (HASCM) { sc = 0.5f / *cmaxp; off = 0.5f; }
    int l = tid & 63, w = tid >> 6;
    int erow = w*16 + (l & 15);
    int i0 = (l >> 4) * 8;
    __syncthreads();
    int eO = eid_s[erow];
    float a0 = eaArr[eO*2]   * sc + off;
    float a1 = eaArr[eO*2+1] * sc + off;
    const float* xr = X + (size_t)src_s[erow]*32 + i0;
    float xv[8];
    *(float4*)&xv[0] = *(const float4*)xr;
    *(float4*)&xv[4] = *(const float4*)(xr + 4);
    f32x4 acc[NTILES];
    #pragma unroll
    for (int nt = 0; nt < NTILES; ++nt) acc[nt] = (f32x4){0.f,0.f,0.f,0.f};
    for (int h = 0; h < 26; ++h) {
        float rv = (h < 25) ? fmaxf(a0*w1[h] + a1*w1[25+h] + b1[h], 0.0f) : 1.0f;
        union { short8 s8; unsigned int u[4]; } av;
        #pragma unroll
        for (int p = 0; p < 4; ++p) {
            float lo = xv[2*p]   * rv;
            float hi = xv[2*p+1] * rv;
            asm("v_cvt_pk_bf16_f32 %0, %1, %2" : "=v"(av.u[p]) : "v"(lo), "v"(hi));
        }
        #pragma unroll
        for (int nt = 0; nt < NTILES; ++nt) {
            short8 bv = *(const short8*)&Wl[(h*NTILES + nt)*512 + l*8];
            acc[nt] = __builtin_amdgcn_mfma_f32_16x16x32_bf16(av.s8, bv, acc[nt], 0, 0, 0);
        }
    }
    int colb = NTOFF_T*16 + (l & 15);
    int er0 = w*16 + (l >> 4)*4;
    #pragma unroll
    for (int nt = 0; nt < NTILES; ++nt) {
        float* col = agg + colb + nt*16;
        float m; int prevd;
        #pragma unroll
        for (int r = 0; r < 4; ++r) {
            int d = dst_s[er0 + r];
            float v = acc[nt][r];
            if (SELF && src_s[er0 + r] == d) v = -__builtin_inff();
            if (r == 0) { prevd = d; m = v; }
            else if (d == prevd) m = fmaxf(m, v);
            else { atomicMaxFloat(col + (size_t)prevd*O, m); prevd = d; m = v; }
        }
        atomicMaxFloat(col + (size_t)prevd*O, m);
    }
}

// ---- conv1 finalize + max_pool over node pairs (cluster1 = arange//2), plus pos2
__global__ __launch_bounds__(256) void k_x2(const float* __restrict__ x,
                                            const float* __restrict__ pos,
                                            const float* __restrict__ root1,
                                            const float* __restrict__ bias1,
                                            float* ws) {
    __shared__ float xs[512];
    int tid = threadIdx.x;
    int n0 = blockIdx.x*16;                      // 16 node rows per block
    for (int idx = tid; idx < 512; idx += 256) xs[idx] = x[n0*32 + idx];
    __syncthreads();
    int o = tid & 31, ci = tid >> 5;             // 8 clusters per block
    int c = blockIdx.x*8 + ci;                   // 25000 = 8*3125 exact
    float b = bias1[o];
    float acc0 = b, acc1 = b;
    const float* x0 = xs + (2*ci)*32;
    const float* x1 = xs + (2*ci+1)*32;
    #pragma unroll
    for (int i = 0; i < 32; ++i) {
        float rw = root1[i*32+o];
        acc0 += x0[i]*rw; acc1 += x1[i]*rw;
    }
    float v0 = ws[OFF_AGG1 + (size_t)(2*c)*32 + o];
    float v1 = ws[OFF_AGG1 + (size_t)(2*c+1)*32 + o];
    if (v0 == -__builtin_inff()) v0 = 0.0f;
    if (v1 == -__builtin_inff()) v1 = 0.0f;
    v0 = eluf(v0 + acc0); v1 = eluf(v1 + acc1);
    ws[OFF_X2 + c*32 + o] = fmaxf(v0, v1);
    if (o < 2) ws[OFF_POS2 + c*2 + o] = 0.5f*(pos[(2*c)*2 + o] + pos[(2*c+1)*2 + o]);
}

// ---- pooled-graph Cartesian: cart + global max (src2/dst2 = idx>>1 on the fly)
__global__ void k_cart(const int* __restrict__ eidx, float* ws) {
    int e = blockIdx.x*256 + threadIdx.x;
    float m = 0.0f;
    if (e < N_EDGES) {
        int s2 = eidx[e] >> 1, d2 = eidx[N_EDGES+e] >> 1;
        float cx = ws[OFF_POS2 + d2*2]     - ws[OFF_POS2 + s2*2];
        float cy = ws[OFF_POS2 + d2*2 + 1] - ws[OFF_POS2 + s2*2 + 1];
        ws[OFF_CART + e*2] = cx; ws[OFF_CART + e*2 + 1] = cy;
        m = fmaxf(fabsf(cx), fabsf(cy));
    }
    #pragma unroll
    for (int off = 32; off; off >>= 1) m = fmaxf(m, __shfl_xor(m, off));
    if ((threadIdx.x & 63) == 0) atomicMax((int*)(ws+OFF_CMAX), __float_as_int(m));
}

// ---- conv2 finalize + max_pool_x over cluster pairs (cluster2 = arange//2)
__global__ __launch_bounds__(256) void k_x4(const float* __restrict__ root2,
                                            const float* __restrict__ bias2,
                                            float* ws) {
    __shared__ float xs[256];
    int tid = threadIdx.x;
    int r0 = blockIdx.x*8;                       // 8 X2 rows per block
    xs[tid] = ws[OFF_X2 + r0*32 + tid];
    __syncthreads();
    int o = tid & 63, ci = tid >> 6;             // 4 out-clusters per block
    int c2 = blockIdx.x*4 + ci;                  // 12500 = 4*3125 exact
    float b = bias2[o];
    float acc0 = b, acc1 = b;
    const float* x0 = xs + (2*ci)*32;
    const float* x1 = xs + (2*ci+1)*32;
    #pragma unroll
    for (int i = 0; i < 32; ++i) {
        float rw = root2[i*64+o];
        acc0 += x0[i]*rw; acc1 += x1[i]*rw;
    }
    float v0 = ws[OFF_AGG2 + (size_t)(2*c2)*64 + o];
    float v1 = ws[OFF_AGG2 + (size_t)(2*c2+1)*64 + o];
    if (v0 == -__builtin_inff()) v0 = 0.0f;
    if (v1 == -__builtin_inff()) v1 = 0.0f;
    v0 = eluf(v0 + acc0); v1 = eluf(v1 + acc1);
    ws[OFF_X4 + c2*64 + o] = fmaxf(v0, v1);
}

// ---- global mean pool: run-length pre-aggregation; batch3[c] = batch[4c+3] (sorted)
__global__ __launch_bounds__(256) void k_gpool(const int* __restrict__ batch, float* ws) {
    int tid = threadIdx.x;
    int o = tid & 63, cl = tid >> 6;
    const int CPB = (C2N + GPB - 1) / GPB;       // 98
    int c0 = blockIdx.x * CPB;
    int c1 = c0 + CPB; if (c1 > C2N) c1 = C2N;
    float acc = 0.0f, cnt = 0.0f;
    int curb = -1;
    for (int c = c0 + cl; c < c1; c += 4) {
        int b = batch[4*c + 3];
        float v = ws[OFF_X4 + c*64 + o];
        if (b != curb) {
            if (curb >= 0) {
                atomicAdd(&ws[OFF_GSUM + curb*64 + o], acc);
                if (o == 0) atomicAdd(&ws[OFF_GCNT + curb], cnt);
            }
            curb = b; acc = 0.0f; cnt = 0.0f;
        }
        acc += v; cnt += 1.0f;
    }
    if (curb >= 0) {
        atomicAdd(&ws[OFF_GSUM + curb*64 + o], acc);
        if (o == 0) atomicAdd(&ws[OFF_GCNT + curb], cnt);
    }
}

__global__ __launch_bounds__(256) void k_head(
    const float* __restrict__ fc1w, const float* __restrict__ fc1b,
    const float* __restrict__ fc2w, const float* __restrict__ fc2b,
    const float* __restrict__ ws, float* __restrict__ out) {
    __shared__ float g_s[32*64], h_s[32*128], l_s[32*32];
    int tid = threadIdx.x;
    for (int idx = tid; idx < 32*64; idx += 256) {
        int b = idx >> 6;
        g_s[idx] = ws[OFF_GSUM + idx] / fmaxf(ws[OFF_GCNT + b], 1.0f);
    }
    __syncthreads();
    for (int idx = tid; idx < 32*128; idx += 256) {
        int b = idx >> 7, f = idx & 127;
        float a = fc1b[f];
        #pragma unroll 8
        for (int i = 0; i < 64; ++i) a += g_s[b*64+i]*fc1w[i*128+f];
        h_s[idx] = eluf(a);
    }
    __syncthreads();
    for (int idx = tid; idx < 32*32; idx += 256) {
        int b = idx >> 5, o = idx & 31;
        float a = fc2b[o];
        #pragma unroll 8
        for (int i = 0; i < 128; ++i) a += h_s[b*128+i]*fc2w[i*32+o];
        l_s[idx] = a;
    }
    __syncthreads();
    if (tid < 32) {
        int b = tid;
        float m = -__builtin_inff();
        for (int o = 0; o < 32; ++o) m = fmaxf(m, l_s[b*32+o]);
        float s = 0.0f;
        for (int o = 0; o < 32; ++o) s += expf(l_s[b*32+o]-m);
        float lg = logf(s);
        for (int o = 0; o < 32; ++o) out[b*32+o] = l_s[b*32+o]-m-lg;
    }
}

extern "C" void kernel_launch(void* const* d_in, const int* in_sizes, int n_in,
                              void* d_out, int out_size, void* d_ws, size_t ws_size,
                              hipStream_t stream) {
    const float* x    = (const float*)d_in[0];
    const float* pos  = (const float*)d_in[1];
    const float* ea   = (const float*)d_in[2];
    const int*   eidx = (const int*)  d_in[3];
    const int*   batch= (const int*)  d_in[4];
    const float* n1w1 = (const float*)d_in[7];
    const float* n1b1 = (const float*)d_in[8];
    const float* n1w2 = (const float*)d_in[9];
    const float* n1b2 = (const float*)d_in[10];
    const float* root1= (const float*)d_in[11];
    const float* bias1= (const float*)d_in[12];
    const float* n2w1 = (const float*)d_in[13];
    const float* n2b1 = (const float*)d_in[14];
    const float* n2w2 = (const float*)d_in[15];
    const float* n2b2 = (const float*)d_in[16];
    const float* root2= (const float*)d_in[17];
    const float* bias2= (const float*)d_in[18];
    const float* fc1w = (const float*)d_in[19];
    const float* fc1b = (const float*)d_in[20];
    const float* fc2w = (const float*)d_in[21];
    const float* fc2b = (const float*)d_in[22];
    float* ws  = (float*)d_ws;
    float* out = (float*)d_out;
    unsigned short* Bb1 = (unsigned short*)(ws + OFF_BB1);
    unsigned short* Bb2 = (unsigned short*)(ws + OFF_BB2);
    const int* dstArr = eidx + N_EDGES;
    const int* perm   = (const int*)(ws + OFF_PERM);

    hipLaunchKernelGGL(k_init, dim3((ZERO_END+255)/256), dim3(256), 0, stream, ws);
    hipLaunchKernelGGL((k_swzf<32>), dim3(104), dim3(256), 0, stream, n1w2, n1b2, Bb1);
    hipLaunchKernelGGL((k_swzf<64>), dim3(208), dim3(256), 0, stream, n2w2, n2b2, Bb2);
    // counting sort of edges by dst (one perm serves both convs: dst sorted => dst>>1 sorted)
    hipLaunchKernelGGL(k_hist, dim3((N_EDGES+255)/256), dim3(256), 0, stream, dstArr, ws);
    hipLaunchKernelGGL(k_scan, dim3(1), dim3(1024), 0, stream, ws);
    hipLaunchKernelGGL(k_scatter, dim3((N_EDGES+255)/256), dim3(256), 0, stream, dstArr, ws);
    // conv1: [E x 832] @ [832 x 32]
    hipLaunchKernelGGL((k_edgemm<32, 2, 0, 0, 0, 0>), dim3(N_EDGES/EPB), dim3(512), 0, stream,
                       x, Bb1, n1w1, n1b1, eidx, dstArr, perm, ea,
                       (const float*)nullptr, ws + OFF_AGG1);
    hipLaunchKernelGGL(k_x2, dim3(C1N/8), dim3(256), 0, stream, x, pos, root1, bias1, ws);
    hipLaunchKernelGGL(k_cart, dim3(N_EDGES/256), dim3(256), 0, stream, eidx, ws);
    // conv2: [E x 832] @ [832 x 64], two dispatches of 32 cols (LDS budget)
    hipLaunchKernelGGL((k_edgemm<64, 2, 0, 1, 1, 1>), dim3(N_EDGES/EPB), dim3(512), 0, stream,
                       ws + OFF_X2, Bb2, n2w1, n2b1, eidx, dstArr, perm,
                       ws + OFF_CART, ws + OFF_CMAX, ws + OFF_AGG2);
    hipLaunchKernelGGL((k_edgemm<64, 2, 2, 1, 1, 1>), dim3(N_EDGES/EPB), dim3(512), 0, stream,
                       ws + OFF_X2, Bb2, n2w1, n2b1, eidx, dstArr, perm,
                       ws + OFF_CART, ws + OFF_CMAX, ws + OFF_AGG2);
    hipLaunchKernelGGL(k_x4, dim3(C2N/4), dim3(256), 0, stream, root2, bias2, ws);
    hipLaunchKernelGGL(k_gpool, dim3(GPB), dim3(256), 0, stream, batch, ws);
    hipLaunchKernelGGL(k_head, dim3(1), dim3(256), 0, stream,
                       fc1w, fc1b, fc2w, fc2b, ws, out);
}

// Round 12
// 304.812 us; speedup vs baseline: 1.2725x; 1.2725x over previous
//
#include <hip/hip_runtime.h>
#include <math.h>

#define N_NODES 50000
#define N_EDGES 160000
#define NB 32
#define C1N 25000
#define C2N 12500
#define EPB 128
#define GPB 128
#define SCAN_BLK 49   // ceil(N_NODES/1024)

// ---- workspace layout (in floats) ----
#define OFF_AGG1 0
#define SZ_AGG1 (N_NODES*32)
#define OFF_AGG2 (OFF_AGG1+SZ_AGG1)
#define SZ_AGG2  (C1N*64)
#define NEG_TOTAL (OFF_AGG2+SZ_AGG2)        // [0,NEG_TOTAL) = -inf
#define OFF_GSUM NEG_TOTAL                  // B*64 (zeroed)
#define OFF_GCNT (OFF_GSUM + NB*64)         // B
#define OFF_CMAX (OFF_GCNT + NB)            // 1 (+3 pad)
#define OFF_HIST (OFF_CMAX + 4)             // N int counters (zeroed; 16B-aligned)
#define ZERO_END (OFF_HIST + N_NODES)
#define OFF_BSUM ZERO_END                   // 64 ints (written by scanA/B)
#define OFF_PERM (OFF_BSUM + 64)            // E ints (dst-sorted edge ids)
#define OFF_X2   (OFF_PERM + N_EDGES)       // C1*32 (written direct)
#define OFF_POS2 (OFF_X2 + C1N*32)          // C1*2
#define OFF_X4   (OFF_POS2 + C1N*2)         // C2*64 (written direct)
#define OFF_CART (OFF_X4 + C2N*64)          // E*2
#define OFF_BB1  (OFF_CART + N_EDGES*2)     // 26*2*512 bf16 = 13312 floats
#define OFF_BB2  (OFF_BB1 + 13312)          // 26*4*512 bf16 = 26624 floats

typedef __attribute__((ext_vector_type(8))) short short8;
typedef __attribute__((ext_vector_type(4))) float f32x4;

__device__ __forceinline__ void atomicMaxFloat(float* addr, float v) {
    if (v >= 0.0f) atomicMax((int*)addr, __float_as_int(v + 0.0f)); // +0.0 canonicalizes -0
    else           atomicMin((unsigned int*)addr, __float_as_uint(v));
}
__device__ __forceinline__ float eluf(float v) { return v > 0.0f ? v : expm1f(v); }
__device__ __forceinline__ unsigned short f2bf(float f) {
    unsigned int u = __float_as_uint(f);
    u += 0x7FFFu + ((u >> 16) & 1u);   // round-to-nearest-even
    return (unsigned short)(u >> 16);
}

__global__ void k_init(float* ws) {
    int i = blockIdx.x*256 + threadIdx.x;
    if (i < ZERO_END) ws[i] = (i < NEG_TOTAL) ? -__builtin_inff() : 0.0f;
}

// ---- counting sort by dst: histogram -> 2-level scan -> scatter
__global__ void k_hist(const int* __restrict__ dstArr, float* ws) {
    int e = blockIdx.x*256 + threadIdx.x;
    if (e < N_EDGES) atomicAdd((int*)(ws+OFF_HIST) + dstArr[e], 1);
}

// per-block scan of 1024 hist entries (in-place local-exclusive) + block sum
__global__ __launch_bounds__(256) void k_scanA(float* ws) {
    int* hist = (int*)(ws + OFF_HIST);
    int* bsum = (int*)(ws + OFF_BSUM);
    __shared__ int ts[256];
    int t = threadIdx.x;
    int base = blockIdx.x*1024 + t*4;
    int v[4] = {0,0,0,0};
    if (base + 3 < N_NODES) *(int4*)v = *(const int4*)(hist + base);
    else { for (int i = 0; i < 4; ++i) v[i] = (base+i < N_NODES) ? hist[base+i] : 0; }
    int s = v[0]+v[1]+v[2]+v[3];
    ts[t] = s; __syncthreads();
    for (int off = 1; off < 256; off <<= 1) {
        int u = (t >= off) ? ts[t-off] : 0;
        __syncthreads();
        ts[t] += u;
        __syncthreads();
    }
    int run = ts[t] - s;                        // exclusive prefix within block
    int w[4];
    #pragma unroll
    for (int i = 0; i < 4; ++i) { w[i] = run; run += v[i]; }
    if (base + 3 < N_NODES) *(int4*)(hist + base) = *(int4*)w;
    else { for (int i = 0; i < 4; ++i) if (base+i < N_NODES) hist[base+i] = w[i]; }
    if (t == 255) bsum[blockIdx.x] = ts[255];
}

// scan the 49 block sums (exclusive)
__global__ void k_scanB(float* ws) {
    int* bsum = (int*)(ws + OFF_BSUM);
    __shared__ int s[64];
    int t = threadIdx.x;
    int v = (t < SCAN_BLK) ? bsum[t] : 0;
    s[t] = v; __syncthreads();
    for (int off = 1; off < 64; off <<= 1) {
        int u = (t >= off) ? s[t-off] : 0;
        __syncthreads();
        s[t] += u;
        __syncthreads();
    }
    if (t < SCAN_BLK) bsum[t] = s[t] - v;
}

__global__ void k_scatter(const int* __restrict__ dstArr, float* ws) {
    int e = blockIdx.x*256 + threadIdx.x;
    if (e < N_EDGES) {
        int d = dstArr[e];
        int p = atomicAdd((int*)(ws+OFF_HIST) + d, 1) + ((int*)(ws+OFF_BSUM))[d >> 10];
        ((int*)(ws+OFF_PERM))[p] = e;
    }
}

// ---- build bf16 B-fragment bank for the [832 x O] GEMM.
// Bf[(h*(O/16)+ntg)*512 + l*8 + j] = W[h*32 + (l>>4)*8+j][ntg*16 + (l&15)]
// W[kk][o]: rows kk=h*32+i; h<25 -> w2[h][i*O+o]; h==25 -> b2[i*O+o]
template<int O>
__global__ void k_swzf(const float* __restrict__ w2, const float* __restrict__ b2,
                       unsigned short* __restrict__ Bf) {
    const int TOT = 26*(O/16)*512;
    int idx = blockIdx.x*256 + threadIdx.x;
    if (idx >= TOT) return;
    int t = idx >> 9;
    int l = (idx >> 3) & 63, j = idx & 7;
    int h = t / (O/16), ntg = t % (O/16);
    int i = (l >> 4)*8 + j;
    int o = ntg*16 + (l & 15);
    float v = (h < 25) ? w2[h*(32*O) + i*O + o] : b2[i*O + o];
    Bf[idx] = f2bf(v);
}

// ---- edge phase as MFMA GEMM over dst-sorted edges:
// [128 edges x 832] @ [832 x 32 cols/dispatch]; z[e,h*32+i]=r[e,h]*x[src_e,i];
// r in-register; W staged in LDS shared by 8 waves; same-dst rows merged
// in-register before the global atomic (sorted => ~deg-length runs).
template<int O, int NTILES, int NTOFF_T, int SELF, int HASCM, int SHIFT>
__global__ __launch_bounds__(512, 4) void k_edgemm(
    const float* __restrict__ X, const unsigned short* __restrict__ Bf,
    const float* __restrict__ w1, const float* __restrict__ b1,
    const int* __restrict__ srcArr, const int* __restrict__ dstArr,
    const int* __restrict__ permArr,
    const float* __restrict__ eaArr, const float* __restrict__ cmaxp,
    float* __restrict__ agg)
{
    __shared__ __align__(16) unsigned short Wl[26*NTILES*512];
    __shared__ int src_s[EPB], dst_s[EPB], eid_s[EPB];
    int tid = threadIdx.x;
    int e0 = blockIdx.x * EPB;
    if (tid < EPB) {
        int e = permArr[e0+tid];
        int s = srcArr[e], d = dstArr[e];
        if (SHIFT) { s >>= 1; d >>= 1; }
        src_s[tid] = s; dst_s[tid] = d; eid_s[tid] = e;
    }
    const int NU4 = 26*NTILES*64;      // uint4 chunks of Wl
    for (int idx = tid; idx < NU4; idx += 512) {
        int q = idx & 63, nt = (idx >> 6) % NTILES, h = idx / (64*NTILES);
        ((uint4*)Wl)[idx] = ((const uint4*)Bf)[(h*(O/16) + NTOFF_T + nt)*64 + q];
    }
    float sc = 1.0f, off = 0.0f;
    if (HASCM) { sc = 0.5f / *cmaxp; off = 0.5f; }
    int l = tid & 63, w = tid >> 6;
    int erow = w*16 + (l & 15);
    int i0 = (l >> 4) * 8;
    __syncthreads();
    int eO = eid_s[erow];
    float a0 = eaArr[eO*2]   * sc + off;
    float a1 = eaArr[eO*2+1] * sc + off;
    const float* xr = X + (size_t)src_s[erow]*32 + i0;
    float xv[8];
    *(float4*)&xv[0] = *(const float4*)xr;
    *(float4*)&xv[4] = *(const float4*)(xr + 4);
    f32x4 acc[NTILES];
    #pragma unroll
    for (int nt = 0; nt < NTILES; ++nt) acc[nt] = (f32x4){0.f,0.f,0.f,0.f};
    for (int h = 0; h < 26; ++h) {
        float rv = (h < 25) ? fmaxf(a0*w1[h] + a1*w1[25+h] + b1[h], 0.0f) : 1.0f;
        union { short8 s8; unsigned int u[4]; } av;
        #pragma unroll
        for (int p = 0; p < 4; ++p) {
            float lo = xv[2*p]   * rv;
            float hi = xv[2*p+1] * rv;
            asm("v_cvt_pk_bf16_f32 %0, %1, %2" : "=v"(av.u[p]) : "v"(lo), "v"(hi));
        }
        #pragma unroll
        for (int nt = 0; nt < NTILES; ++nt) {
            short8 bv = *(const short8*)&Wl[(h*NTILES + nt)*512 + l*8];
            acc[nt] = __builtin_amdgcn_mfma_f32_16x16x32_bf16(av.s8, bv, acc[nt], 0, 0, 0);
        }
    }
    int colb = NTOFF_T*16 + (l & 15);
    int er0 = w*16 + (l >> 4)*4;
    #pragma unroll
    for (int nt = 0; nt < NTILES; ++nt) {
        float* col = agg + colb + nt*16;
        float m; int prevd;
        #pragma unroll
        for (int r = 0; r < 4; ++r) {
            int d = dst_s[er0 + r];
            float v = acc[nt][r];
            if (SELF && src_s[er0 + r] == d) v = -__builtin_inff();
            if (r == 0) { prevd = d; m = v; }
            else if (d == prevd) m = fmaxf(m, v);
            else { atomicMaxFloat(col + (size_t)prevd*O, m); prevd = d; m = v; }
        }
        atomicMaxFloat(col + (size_t)prevd*O, m);
    }
}

// ---- conv1 finalize + max_pool over node pairs (cluster1 = arange//2), plus pos2
__global__ __launch_bounds__(256) void k_x2(const float* __restrict__ x,
                                            const float* __restrict__ pos,
                                            const float* __restrict__ root1,
                                            const float* __restrict__ bias1,
                                            float* ws) {
    __shared__ float xs[512];
    int tid = threadIdx.x;
    int n0 = blockIdx.x*16;                      // 16 node rows per block
    for (int idx = tid; idx < 512; idx += 256) xs[idx] = x[n0*32 + idx];
    __syncthreads();
    int o = tid & 31, ci = tid >> 5;             // 8 clusters per block
    int c = blockIdx.x*8 + ci;                   // 25000 = 8*3125 exact
    float b = bias1[o];
    float acc0 = b, acc1 = b;
    const float* x0 = xs + (2*ci)*32;
    const float* x1 = xs + (2*ci+1)*32;
    #pragma unroll
    for (int i = 0; i < 32; ++i) {
        float rw = root1[i*32+o];
        acc0 += x0[i]*rw; acc1 += x1[i]*rw;
    }
    float v0 = ws[OFF_AGG1 + (size_t)(2*c)*32 + o];
    float v1 = ws[OFF_AGG1 + (size_t)(2*c+1)*32 + o];
    if (v0 == -__builtin_inff()) v0 = 0.0f;
    if (v1 == -__builtin_inff()) v1 = 0.0f;
    v0 = eluf(v0 + acc0); v1 = eluf(v1 + acc1);
    ws[OFF_X2 + c*32 + o] = fmaxf(v0, v1);
    if (o < 2) ws[OFF_POS2 + c*2 + o] = 0.5f*(pos[(2*c)*2 + o] + pos[(2*c+1)*2 + o]);
}

// ---- pooled-graph Cartesian: cart + global max (src2/dst2 = idx>>1 on the fly)
__global__ void k_cart(const int* __restrict__ eidx, float* ws) {
    int e = blockIdx.x*256 + threadIdx.x;
    float m = 0.0f;
    if (e < N_EDGES) {
        int s2 = eidx[e] >> 1, d2 = eidx[N_EDGES+e] >> 1;
        float cx = ws[OFF_POS2 + d2*2]     - ws[OFF_POS2 + s2*2];
        float cy = ws[OFF_POS2 + d2*2 + 1] - ws[OFF_POS2 + s2*2 + 1];
        ws[OFF_CART + e*2] = cx; ws[OFF_CART + e*2 + 1] = cy;
        m = fmaxf(fabsf(cx), fabsf(cy));
    }
    #pragma unroll
    for (int off = 32; off; off >>= 1) m = fmaxf(m, __shfl_xor(m, off));
    if ((threadIdx.x & 63) == 0) atomicMax((int*)(ws+OFF_CMAX), __float_as_int(m));
}

// ---- conv2 finalize + max_pool_x over cluster pairs (cluster2 = arange//2)
__global__ __launch_bounds__(256) void k_x4(const float* __restrict__ root2,
                                            const float* __restrict__ bias2,
                                            float* ws) {
    __shared__ float xs[256];
    int tid = threadIdx.x;
    int r0 = blockIdx.x*8;                       // 8 X2 rows per block
    xs[tid] = ws[OFF_X2 + r0*32 + tid];
    __syncthreads();
    int o = tid & 63, ci = tid >> 6;             // 4 out-clusters per block
    int c2 = blockIdx.x*4 + ci;                  // 12500 = 4*3125 exact
    float b = bias2[o];
    float acc0 = b, acc1 = b;
    const float* x0 = xs + (2*ci)*32;
    const float* x1 = xs + (2*ci+1)*32;
    #pragma unroll
    for (int i = 0; i < 32; ++i) {
        float rw = root2[i*64+o];
        acc0 += x0[i]*rw; acc1 += x1[i]*rw;
    }
    float v0 = ws[OFF_AGG2 + (size_t)(2*c2)*64 + o];
    float v1 = ws[OFF_AGG2 + (size_t)(2*c2+1)*64 + o];
    if (v0 == -__builtin_inff()) v0 = 0.0f;
    if (v1 == -__builtin_inff()) v1 = 0.0f;
    v0 = eluf(v0 + acc0); v1 = eluf(v1 + acc1);
    ws[OFF_X4 + c2*64 + o] = fmaxf(v0, v1);
}

// ---- global mean pool: run-length pre-aggregation; batch3[c] = batch[4c+3] (sorted)
__global__ __launch_bounds__(256) void k_gpool(const int* __restrict__ batch, float* ws) {
    int tid = threadIdx.x;
    int o = tid & 63, cl = tid >> 6;
    const int CPB = (C2N + GPB - 1) / GPB;       // 98
    int c0 = blockIdx.x * CPB;
    int c1 = c0 + CPB; if (c1 > C2N) c1 = C2N;
    float acc = 0.0f, cnt = 0.0f;
    int curb = -1;
    for (int c = c0 + cl; c < c1; c += 4) {
        int b = batch[4*c + 3];
        float v = ws[OFF_X4 + c*64 + o];
        if (b != curb) {
            if (curb >= 0) {
                atomicAdd(&ws[OFF_GSUM + curb*64 + o], acc);
                if (o == 0) atomicAdd(&ws[OFF_GCNT + curb], cnt);
            }
            curb = b; acc = 0.0f; cnt = 0.0f;
        }
        acc += v; cnt += 1.0f;
    }
    if (curb >= 0) {
        atomicAdd(&ws[OFF_GSUM + curb*64 + o], acc);
        if (o == 0) atomicAdd(&ws[OFF_GCNT + curb], cnt);
    }
}

__global__ __launch_bounds__(256) void k_head(
    const float* __restrict__ fc1w, const float* __restrict__ fc1b,
    const float* __restrict__ fc2w, const float* __restrict__ fc2b,
    const float* __restrict__ ws, float* __restrict__ out) {
    __shared__ float g_s[32*64], h_s[32*128], l_s[32*32];
    int tid = threadIdx.x;
    for (int idx = tid; idx < 32*64; idx += 256) {
        int b = idx >> 6;
        g_s[idx] = ws[OFF_GSUM + idx] / fmaxf(ws[OFF_GCNT + b], 1.0f);
    }
    __syncthreads();
    for (int idx = tid; idx < 32*128; idx += 256) {
        int b = idx >> 7, f = idx & 127;
        float a = fc1b[f];
        #pragma unroll 8
        for (int i = 0; i < 64; ++i) a += g_s[b*64+i]*fc1w[i*128+f];
        h_s[idx] = eluf(a);
    }
    __syncthreads();
    for (int idx = tid; idx < 32*32; idx += 256) {
        int b = idx >> 5, o = idx & 31;
        float a = fc2b[o];
        #pragma unroll 8
        for (int i = 0; i < 128; ++i) a += h_s[b*128+i]*fc2w[i*32+o];
        l_s[idx] = a;
    }
    __syncthreads();
    if (tid < 32) {
        int b = tid;
        float m = -__builtin_inff();
        for (int o = 0; o < 32; ++o) m = fmaxf(m, l_s[b*32+o]);
        float s = 0.0f;
        for (int o = 0; o < 32; ++o) s += expf(l_s[b*32+o]-m);
        float lg = logf(s);
        for (int o = 0; o < 32; ++o) out[b*32+o] = l_s[b*32+o]-m-lg;
    }
}

extern "C" void kernel_launch(void* const* d_in, const int* in_sizes, int n_in,
                              void* d_out, int out_size, void* d_ws, size_t ws_size,
                              hipStream_t stream) {
    const float* x    = (const float*)d_in[0];
    const float* pos  = (const float*)d_in[1];
    const float* ea   = (const float*)d_in[2];
    const int*   eidx = (const int*)  d_in[3];
    const int*   batch= (const int*)  d_in[4];
    const float* n1w1 = (const float*)d_in[7];
    const float* n1b1 = (const float*)d_in[8];
    const float* n1w2 = (const float*)d_in[9];
    const float* n1b2 = (const float*)d_in[10];
    const float* root1= (const float*)d_in[11];
    const float* bias1= (const float*)d_in[12];
    const float* n2w1 = (const float*)d_in[13];
    const float* n2b1 = (const float*)d_in[14];
    const float* n2w2 = (const float*)d_in[15];
    const float* n2b2 = (const float*)d_in[16];
    const float* root2= (const float*)d_in[17];
    const float* bias2= (const float*)d_in[18];
    const float* fc1w = (const float*)d_in[19];
    const float* fc1b = (const float*)d_in[20];
    const float* fc2w = (const float*)d_in[21];
    const float* fc2b = (const float*)d_in[22];
    float* ws  = (float*)d_ws;
    float* out = (float*)d_out;
    unsigned short* Bb1 = (unsigned short*)(ws + OFF_BB1);
    unsigned short* Bb2 = (unsigned short*)(ws + OFF_BB2);
    const int* dstArr = eidx + N_EDGES;
    const int* perm   = (const int*)(ws + OFF_PERM);

    hipLaunchKernelGGL(k_init, dim3((ZERO_END+255)/256), dim3(256), 0, stream, ws);
    hipLaunchKernelGGL((k_swzf<32>), dim3(104), dim3(256), 0, stream, n1w2, n1b2, Bb1);
    hipLaunchKernelGGL((k_swzf<64>), dim3(208), dim3(256), 0, stream, n2w2, n2b2, Bb2);
    // counting sort of edges by dst (one perm serves both convs: dst sorted => dst>>1 sorted)
    hipLaunchKernelGGL(k_hist, dim3((N_EDGES+255)/256), dim3(256), 0, stream, dstArr, ws);
    hipLaunchKernelGGL(k_scanA, dim3(SCAN_BLK), dim3(256), 0, stream, ws);
    hipLaunchKernelGGL(k_scanB, dim3(1), dim3(64), 0, stream, ws);
    hipLaunchKernelGGL(k_scatter, dim3((N_EDGES+255)/256), dim3(256), 0, stream, dstArr, ws);
    // conv1: [E x 832] @ [832 x 32]
    hipLaunchKernelGGL((k_edgemm<32, 2, 0, 0, 0, 0>), dim3(N_EDGES/EPB), dim3(512), 0, stream,
                       x, Bb1, n1w1, n1b1, eidx, dstArr, perm, ea,
                       (const float*)nullptr, ws + OFF_AGG1);
    hipLaunchKernelGGL(k_x2, dim3(C1N/8), dim3(256), 0, stream, x, pos, root1, bias1, ws);
    hipLaunchKernelGGL(k_cart, dim3(N_EDGES/256), dim3(256), 0, stream, eidx, ws);
    // conv2: [E x 832] @ [832 x 64], two dispatches of 32 cols (LDS budget)
    hipLaunchKernelGGL((k_edgemm<64, 2, 0, 1, 1, 1>), dim3(N_EDGES/EPB), dim3(512), 0, stream,
                       ws + OFF_X2, Bb2, n2w1, n2b1, eidx, dstArr, perm,
                       ws + OFF_CART, ws + OFF_CMAX, ws + OFF_AGG2);
    hipLaunchKernelGGL((k_edgemm<64, 2, 2, 1, 1, 1>), dim3(N_EDGES/EPB), dim3(512), 0, stream,
                       ws + OFF_X2, Bb2, n2w1, n2b1, eidx, dstArr, perm,
                       ws + OFF_CART, ws + OFF_CMAX, ws + OFF_AGG2);
    hipLaunchKernelGGL(k_x4, dim3(C2N/4), dim3(256), 0, stream, root2, bias2, ws);
    hipLaunchKernelGGL(k_gpool, dim3(GPB), dim3(256), 0, stream, batch, ws);
    hipLaunchKernelGGL(k_head, dim3(1), dim3(256), 0, stream,
                       fc1w, fc1b, fc2w, fc2b, ws, out);
}